// Round 7
// baseline (403646.851 us; speedup 1.0000x reference)
//
#include <hip/hip_runtime.h>

// RNNDetector: 2-layer LSTM (H=64), T=262144 sequential steps + 16-wide head.
// ROUNDS 1-6 LESSON (counter-verified): duration was invariant at ~1850-1900
// cyc/step across six structurally different kernels because all 192KB of f32
// weights stream from L1/L2 every step (the allocator always split the
// invariant live ranges; 3 register-forcing attempts failed). 192KB/1900cyc
// = 101 B/cyc = per-CU L2 read BW -> the binding pipe is L2 BYTES.
// THIS ROUND: halve the bytes. A pre-pass kernel packs Whh0/Wih1/Whh1 to
// bf16 pairs in d_ws (96KB total); the main loop streams bf16 and unpacks
// with shifts (f32 math unchanged). Weight reloading is now the DESIGN.
// Geometry unchanged from R5 (validated): K-shard each dot across 4 lanes.
//   Lane (q,r,g): q=k-shard(2b), r=gate(2b), g=element-group(4b); owns rows
//   r*64+4g..+3 x 16-col chunk (L0) / 32-col chunk of Wih1|Whh1 (L1).
//   Shard-reduce xor(1),xor(2); gate exchange xor(8),xor(4). One barrier/step.
// Pipeline: step s computes h0(s), h1(s-1), out(s-2); h double-buffered.

constexpr int T = 262144;

typedef float v4 __attribute__((ext_vector_type(4)));

__device__ __forceinline__ float rcp_f(float x) { return __builtin_amdgcn_rcpf(x); }

__device__ __forceinline__ unsigned bf16rne(float f) {
  unsigned u = __float_as_uint(f);
  return (u + 0x7fffu + ((u >> 16) & 1u)) >> 16;   // round-to-nearest-even
}

#define LOW(u)  __uint_as_float((u) << 16)
#define HIW(u)  __uint_as_float((u) & 0xffff0000u)

// 16-col row-dot: two packed uint4 (16 bf16 weights) vs H0..H3 (16 f32 h)
#define DOT16B(a, U, V, Ha, Hb, Hc, Hd)                                        \
  a = fmaf(LOW(U.x), Ha.x, a); a = fmaf(HIW(U.x), Ha.y, a);                    \
  a = fmaf(LOW(U.y), Ha.z, a); a = fmaf(HIW(U.y), Ha.w, a);                    \
  a = fmaf(LOW(U.z), Hb.x, a); a = fmaf(HIW(U.z), Hb.y, a);                    \
  a = fmaf(LOW(U.w), Hb.z, a); a = fmaf(HIW(U.w), Hb.w, a);                    \
  a = fmaf(LOW(V.x), Hc.x, a); a = fmaf(HIW(V.x), Hc.y, a);                    \
  a = fmaf(LOW(V.y), Hc.z, a); a = fmaf(HIW(V.y), Hc.w, a);                    \
  a = fmaf(LOW(V.z), Hd.x, a); a = fmaf(HIW(V.z), Hd.y, a);                    \
  a = fmaf(LOW(V.w), Hd.z, a); a = fmaf(HIW(V.w), Hd.w, a);

#define RED4S(a0,a1,a2,a3, d) { a0 += __shfl_xor(a0, d); a1 += __shfl_xor(a1, d); \
                                a2 += __shfl_xor(a2, d); a3 += __shfl_xor(a3, d); }

// R2/R5-validated gate algebra, shuffle distances 8 (r^2) and 4 (r^1).
__device__ __forceinline__ float gate_update(float pre, int r, float& c) {
  const bool isG = (r == 2);
  float z  = fminf(fmaxf(pre * (isG ? 2.f : 1.f), -30.f), 30.f);
  float ex = __expf(-z);
  float a  = (isG ? (1.f - ex) : 1.f) * rcp_f(1.f + ex);
  float b2 = __shfl_xor(a, 8);          // partner gate r^2
  float fo = (r & 2) ? b2 : a;
  float m1 = (r & 1) ? fo : a;
  float m2 = (r & 1) ? c  : b2;
  float p  = m1 * m2;
  float cn = p + __shfl_xor(p, 4);      // i*g + f*c in all 4 lanes
  c = cn;
  float zz = fminf(fmaxf(cn, -15.f), 15.f);
  float e2 = __expf(-2.f * zz);
  float th = (1.f - e2) * rcp_f(1.f + e2);
  float oo = (r & 2) ? a : b2;          // r==3 holds o
  return oo * th;
}

// ---------- pre-pass: pack 3 weight matrices (f32 -> bf16 pairs) ----------
// ws dwords: [0,8192) Whh0 | [8192,16384) Wih1 | [16384,24576) Whh1
__global__ void pack_bf16_k(const float* __restrict__ Whh0,
                            const float* __restrict__ Wih1,
                            const float* __restrict__ Whh1,
                            unsigned* __restrict__ ws) {
  int i = blockIdx.x * 256 + threadIdx.x;       // 0..24575
  const float* src; int b;
  if (i < 8192)       { src = Whh0; b = i; }
  else if (i < 16384) { src = Wih1; b = i - 8192; }
  else                { src = Whh1; b = i - 16384; }
  ws[i] = bf16rne(src[2 * b]) | (bf16rne(src[2 * b + 1]) << 16);
}

__global__ __launch_bounds__(512) void rnn_fused(
    const float* __restrict__ y,
    const float* __restrict__ Wih0, const float* __restrict__ bih0,
    const float* __restrict__ bhh0,
    const float* __restrict__ bih1, const float* __restrict__ bhh1,
    const float* __restrict__ Wlin, const float* __restrict__ blin,
    const unsigned* __restrict__ wb,           // packed bf16 weights (d_ws)
    float* __restrict__ out)
{
  const int tid  = threadIdx.x;
  const bool isL1 = tid >= 256;
  const int l  = tid & 255;
  const int q  = l & 3;                 // k-shard
  const int r  = (l >> 2) & 3;          // gate 0=i 1=f 2=g 3=o
  const int g  = l >> 4;                // element group 0..15
  const int e  = 4 * g + q;             // this lane's element
  const int jrow = r * 64 + e;          // bias row
  const int r0 = r * 64 + 4 * g;        // first of the 4 owned rows

  // LDS: h0[2][64] @0, h1[2][64] @136 (8-float skew; 0 conflicts, R5-verified)
  __shared__ __align__(16) float smem[272];
  if (tid < 272) smem[tid] = 0.f;
  __syncthreads();

  if (!isL1) {
    // ===== layer 0 (+ head) =====
    const unsigned* w0p = wb + r0 * 32 + 8 * q;   // row r0, cols 16q.. (bf16 pairs)
    float bb  = bih0[jrow] + bhh0[jrow];
    float wi0 = Wih0[jrow];
    const int hm = tid >> 4, hk = tid & 15;       // head mapping (R4/R5-verified)
    v4 WL = *((const v4*)(Wlin + hm * 64) + hk);
    float bl = (hk == 0) ? blin[hm] : 0.f;
    const float* hbase = smem + 16 * q;           // h0 chunk base
    const float* hhead = smem + 136 + 4 * hk;     // head h1 slice
    float c = 0.f;
    float yq0 = y[0], yq1 = y[1], yq2 = y[2], yq3 = y[3];

    #pragma unroll 1
    for (int s = 0; s < T + 2; ++s) {
      const int cur = s & 1, nxt = cur ^ 1;
      // ---- head: out(s-2) from h1[cur] ----
      if (s >= 2) {
        v4 hh = *(const v4*)(hhead + cur * 64);
        v4 tt = WL * hh;
        float p2 = (tt.x + tt.y) + (tt.z + tt.w);
        p2 += __shfl_xor(p2, 1);
        p2 += __shfl_xor(p2, 2);
        p2 += __shfl_xor(p2, 4);
        p2 += __shfl_xor(p2, 8);
        if (hk == 0) out[(s - 2) * 16 + hm] = p2 + bl;
      }
      // ---- layer 0: h0(s) from h0[cur], y[s] ----
      if (s < T) {
        float y_nxt = (s + 4 < T) ? y[s + 4] : 0.f;
        // weight stream: 8 x dwordx4 of packed bf16 (rows r0..r0+3)
        uint4 U0 = *(const uint4*)(w0p +  0), V0 = *(const uint4*)(w0p +  4);
        uint4 U1 = *(const uint4*)(w0p + 32), V1 = *(const uint4*)(w0p + 36);
        uint4 U2 = *(const uint4*)(w0p + 64), V2 = *(const uint4*)(w0p + 68);
        uint4 U3 = *(const uint4*)(w0p + 96), V3 = *(const uint4*)(w0p + 100);
        const v4* hp = (const v4*)(hbase + cur * 64);
        v4 Ha = hp[0], Hb = hp[1], Hc = hp[2], Hd = hp[3];
        float a0 = 0.f, a1 = 0.f, a2 = 0.f, a3 = 0.f;
        DOT16B(a0, U0, V0, Ha, Hb, Hc, Hd);
        DOT16B(a1, U1, V1, Ha, Hb, Hc, Hd);
        DOT16B(a2, U2, V2, Ha, Hb, Hc, Hd);
        DOT16B(a3, U3, V3, Ha, Hb, Hc, Hd);
        RED4S(a0, a1, a2, a3, 1);
        RED4S(a0, a1, a2, a3, 2);                  // sum shards q
        float s1 = (q & 1) ? a1 : a0;
        float s2 = (q & 1) ? a3 : a2;
        float pre = ((q & 2) ? s2 : s1) + fmaf(yq0, wi0, bb);
        float h = gate_update(pre, r, c);
        if (r == 3) smem[nxt * 64 + e] = h;
        yq0 = yq1; yq1 = yq2; yq2 = yq3; yq3 = y_nxt;
      }
      __syncthreads();
    }
  } else {
    // ===== layer 1 =====
    // q<2 -> Wih1 (vs h0), q>=2 -> Whh1 (vs h1); cols 32(q&1)..+31
    const unsigned* w1p = wb + ((q < 2) ? 8192 : 16384)
                             + r0 * 32 + 16 * (q & 1);
    float bb = bih1[jrow] + bhh1[jrow];
    const float* hbase = ((q < 2) ? smem : smem + 136) + 32 * (q & 1);
    float c = 0.f;

    #pragma unroll 1
    for (int s = 0; s < T + 2; ++s) {
      const int cur = s & 1, nxt = cur ^ 1;
      // ---- layer 1: h1(s-1) from h0[cur]=h0(s-1), h1[cur]=h1(s-2) ----
      if (s >= 1 && s <= T) {
        uint4 A0 = *(const uint4*)(w1p +  0),  B0 = *(const uint4*)(w1p +  4);
        uint4 C0 = *(const uint4*)(w1p +  8),  D0 = *(const uint4*)(w1p + 12);
        uint4 A1 = *(const uint4*)(w1p + 32),  B1 = *(const uint4*)(w1p + 36);
        uint4 C1 = *(const uint4*)(w1p + 40),  D1 = *(const uint4*)(w1p + 44);
        uint4 A2 = *(const uint4*)(w1p + 64),  B2 = *(const uint4*)(w1p + 68);
        uint4 C2 = *(const uint4*)(w1p + 72),  D2 = *(const uint4*)(w1p + 76);
        uint4 A3 = *(const uint4*)(w1p + 96),  B3 = *(const uint4*)(w1p + 100);
        uint4 C3 = *(const uint4*)(w1p + 104), D3 = *(const uint4*)(w1p + 108);
        const v4* hp = (const v4*)(hbase + cur * 64);
        v4 Ha = hp[0], Hb = hp[1], Hc = hp[2], Hd = hp[3];
        v4 He = hp[4], Hf = hp[5], Hg = hp[6], Hh = hp[7];
        float a0 = 0.f, a1 = 0.f, a2 = 0.f, a3 = 0.f;
        DOT16B(a0, A0, B0, Ha, Hb, Hc, Hd); DOT16B(a0, C0, D0, He, Hf, Hg, Hh);
        DOT16B(a1, A1, B1, Ha, Hb, Hc, Hd); DOT16B(a1, C1, D1, He, Hf, Hg, Hh);
        DOT16B(a2, A2, B2, Ha, Hb, Hc, Hd); DOT16B(a2, C2, D2, He, Hf, Hg, Hh);
        DOT16B(a3, A3, B3, Ha, Hb, Hc, Hd); DOT16B(a3, C3, D3, He, Hf, Hg, Hh);
        RED4S(a0, a1, a2, a3, 1);
        RED4S(a0, a1, a2, a3, 2);                  // full 128-K sum
        float s1 = (q & 1) ? a1 : a0;
        float s2 = (q & 1) ? a3 : a2;
        float pre = ((q & 2) ? s2 : s1) + bb;
        float h = gate_update(pre, r, c);
        if (r == 3) smem[136 + nxt * 64 + e] = h;
      }
      __syncthreads();
    }
  }
}

extern "C" void kernel_launch(void* const* d_in, const int* in_sizes, int n_in,
                              void* d_out, int out_size, void* d_ws, size_t ws_size,
                              hipStream_t stream) {
  const float* y    = (const float*)d_in[0];
  const float* Wih0 = (const float*)d_in[1];
  const float* Whh0 = (const float*)d_in[2];
  const float* bih0 = (const float*)d_in[3];
  const float* bhh0 = (const float*)d_in[4];
  const float* Wih1 = (const float*)d_in[5];
  const float* Whh1 = (const float*)d_in[6];
  const float* bih1 = (const float*)d_in[7];
  const float* bhh1 = (const float*)d_in[8];
  const float* Wlin = (const float*)d_in[9];
  const float* blin = (const float*)d_in[10];
  unsigned* wb = (unsigned*)d_ws;               // 24576 dwords = 96KB

  pack_bf16_k<<<dim3(96), dim3(256), 0, stream>>>(Whh0, Wih1, Whh1, wb);
  rnn_fused<<<dim3(1), dim3(512), 0, stream>>>(
      y, Wih0, bih0, bhh0, bih1, bhh1, Wlin, blin, wb, (float*)d_out);
}

// Round 8
// 198235.107 us; speedup vs baseline: 2.0362x; 2.0362x over previous
//
#include <hip/hip_runtime.h>

// RNNDetector: 2-layer LSTM (H=64), T=262144 sequential steps + 16-wide head.
// ROUNDS 1-7 LESSON (fits all 7 data points): per-step time ~= (#serialized
// weight-load batches) x (~450cyc L2 latency). The register allocator NEVER
// keeps the per-lane weights resident (84/48 VGPRs every round, 3 forcing
// attempts failed) and limits loads in flight, so every step pays 3-8 exposed
// L2 round-trips (1830-3800 cyc/step). R7's bf16 repack halved bytes but
// doubled batches -> 2x SLOWER: latency-batch bound, not bandwidth bound.
// THIS ROUND: hard-coded physical VGPRs via inline asm. Prepass packs
// per-lane-contiguous weight slices into d_ws; init asm loads them ONCE into
// v[100:163] (L0) / v[100:227] (L1) (clobber-reserved, vgpr_count>=228 ->
// 2 waves/SIMD, fine for the single 512-thread block); per-step asm does
// 4/8 ds_read_b128 (h chunk) + 64/128 v_fmac_f32 on fixed regs. ZERO weight
// loads per step. Glue (shard-reduce xor1/xor2, gate exchange xor8/xor4,
// head, pipeline, barrier) is R5's validated C++ verbatim.
// Lane (q,r,g): q=k-shard(2b), r=gate(2b), g=element-group(4b); lane owns
// rows r*64+4g..+3 x 16-col chunk (L0) / 32-col chunk of Wih1|Whh1 (L1),
// packed column-major in its d_ws slice. One barrier/step.
// Pipeline: step s computes h0(s), h1(s-1), out(s-2); h double-buffered.

constexpr int T = 262144;

typedef float v4 __attribute__((ext_vector_type(4)));

__device__ __forceinline__ float rcp_f(float x) { return __builtin_amdgcn_rcpf(x); }

// ---- asm text generators ----
#define FM(acc, h, w) "v_fmac_f32 v" #acc ", v" #h ", v" #w "\n\t"
#define C0(h, w0, w1, w2, w3) FM(32,h,w0) FM(33,h,w1) FM(34,h,w2) FM(35,h,w3)
#define C1(h, w0, w1, w2, w3) FM(48,h,w0) FM(49,h,w1) FM(50,h,w2) FM(51,h,w3)
#define GL(r0, r1, off) \
  "global_load_dwordx4 v[" #r0 ":" #r1 "], %0, off offset:" #off "\n\t"
#define DR(r0, r1, off) "ds_read_b128 v[" #r0 ":" #r1 "], %4 offset:" #off "\n\t"

// R2/R5-validated gate algebra, shuffle distances 8 (r^2) and 4 (r^1).
__device__ __forceinline__ float gate_update(float pre, int r, float& c) {
  const bool isG = (r == 2);
  float z  = fminf(fmaxf(pre * (isG ? 2.f : 1.f), -30.f), 30.f);
  float ex = __expf(-z);
  float a  = (isG ? (1.f - ex) : 1.f) * rcp_f(1.f + ex);
  float b2 = __shfl_xor(a, 8);          // partner gate r^2
  float fo = (r & 2) ? b2 : a;
  float m1 = (r & 1) ? fo : a;
  float m2 = (r & 1) ? c  : b2;
  float p  = m1 * m2;
  float cn = p + __shfl_xor(p, 4);      // i*g + f*c in all 4 lanes
  c = cn;
  float zz = fminf(fmaxf(cn, -15.f), 15.f);
  float e2 = __expf(-2.f * zz);
  float th = (1.f - e2) * rcp_f(1.f + e2);
  float oo = (r & 2) ? a : b2;          // r==3 holds o
  return oo * th;
}

// ---- prepass: pack per-lane-contiguous weight slices (f32) into d_ws ----
// L0 lane l (0..255): ws[l*64 + k*4 + rr]        = Whh0[(r*64+4g+rr)*64 + 16q+k]
// L1 lane l (0..255): ws[16384 + l*128 + k*4+rr] = M[(r*64+4g+rr)*64 + c0+k]
//   (M = q<2 ? Wih1 : Whh1, c0 = 32*(q&1))
__global__ void pack_slices(const float* __restrict__ Whh0,
                            const float* __restrict__ Wih1,
                            const float* __restrict__ Whh1,
                            float* __restrict__ ws) {
  int i = blockIdx.x * 256 + threadIdx.x;          // 0..49151
  if (i < 16384) {
    int l = i >> 6, rem = i & 63, k = rem >> 2, rr = rem & 3;
    int q = l & 3, r = (l >> 2) & 3, g = l >> 4;
    ws[i] = Whh0[(r * 64 + 4 * g + rr) * 64 + 16 * q + k];
  } else {
    int i2 = i - 16384;
    int l = i2 >> 7, rem = i2 & 127, k = rem >> 2, rr = rem & 3;
    int q = l & 3, r = (l >> 2) & 3, g = l >> 4;
    const float* M = (q < 2) ? Wih1 : Whh1;
    ws[i] = M[(r * 64 + 4 * g + rr) * 64 + 32 * (q & 1) + k];
  }
}

__global__ __launch_bounds__(512) void rnn_fused(
    const float* __restrict__ y,
    const float* __restrict__ Wih0, const float* __restrict__ bih0,
    const float* __restrict__ bhh0,
    const float* __restrict__ bih1, const float* __restrict__ bhh1,
    const float* __restrict__ Wlin, const float* __restrict__ blin,
    const float* __restrict__ ws,              // packed per-lane slices
    float* __restrict__ out)
{
  const int tid  = threadIdx.x;
  const bool isL1 = tid >= 256;
  const int l  = tid & 255;
  const int q  = l & 3;                 // k-shard
  const int r  = (l >> 2) & 3;          // gate 0=i 1=f 2=g 3=o
  const int g  = l >> 4;                // element group 0..15
  const int e  = 4 * g + q;             // this lane's element
  const int jrow = r * 64 + e;          // bias row

  // LDS: h0[2][64] @0, h1[2][64] @136 (8-float skew; 0 conflicts, R5-verified)
  __shared__ __align__(16) float smem[272];
  if (tid < 272) smem[tid] = 0.f;
  __syncthreads();

  if (!isL1) {
    // ===== layer 0 (+ head): weights -> v[100:163], ONCE =====
    unsigned long long wbase = (unsigned long long)(uintptr_t)(ws + l * 64);
    asm volatile(
      GL(100,103,0)   GL(104,107,16)  GL(108,111,32)  GL(112,115,48)
      GL(116,119,64)  GL(120,123,80)  GL(124,127,96)  GL(128,131,112)
      GL(132,135,128) GL(136,139,144) GL(140,143,160) GL(144,147,176)
      GL(148,151,192) GL(152,155,208) GL(156,159,224) GL(160,163,240)
      "s_waitcnt vmcnt(0)\n\t"
      :: "v"(wbase)
      : "v100","v101","v102","v103","v104","v105","v106","v107",
        "v108","v109","v110","v111","v112","v113","v114","v115",
        "v116","v117","v118","v119","v120","v121","v122","v123",
        "v124","v125","v126","v127","v128","v129","v130","v131",
        "v132","v133","v134","v135","v136","v137","v138","v139",
        "v140","v141","v142","v143","v144","v145","v146","v147",
        "v148","v149","v150","v151","v152","v153","v154","v155",
        "v156","v157","v158","v159","v160","v161","v162","v163","memory");

    float bb  = bih0[jrow] + bhh0[jrow];
    float wi0 = Wih0[jrow];
    const int hm = tid >> 4, hk = tid & 15;       // head mapping (R4/R5-verified)
    v4 WL = *((const v4*)(Wlin + hm * 64) + hk);
    float bl = (hk == 0) ? blin[hm] : 0.f;
    const float* hbase = smem + 16 * q;           // h0 chunk base
    const float* hhead = smem + 136 + 4 * hk;     // head h1 slice
    float c = 0.f;
    float yq0 = y[0], yq1 = y[1], yq2 = y[2], yq3 = y[3];

    #pragma unroll 1
    for (int s = 0; s < T + 2; ++s) {
      const int cur = s & 1, nxt = cur ^ 1;
      // ---- head: out(s-2) from h1[cur] ----
      if (s >= 2) {
        v4 hh = *(const v4*)(hhead + cur * 64);
        v4 tt = WL * hh;
        float p2 = (tt.x + tt.y) + (tt.z + tt.w);
        p2 += __shfl_xor(p2, 1);
        p2 += __shfl_xor(p2, 2);
        p2 += __shfl_xor(p2, 4);
        p2 += __shfl_xor(p2, 8);
        if (hk == 0) out[(s - 2) * 16 + hm] = p2 + bl;
      }
      // ---- layer 0: h0(s) from h0[cur], y[s] ----
      if (s < T) {
        float y_nxt = (s + 4 < T) ? y[s + 4] : 0.f;
        // LDS byte addr (shared aperture is 4GiB-aligned -> low 32b = offset)
        unsigned haddr = (unsigned)(uintptr_t)(hbase + cur * 64);
        float a0, a1, a2, a3;
        asm volatile(
          "v_mov_b32 v32, 0\n\t" "v_mov_b32 v33, 0\n\t"
          "v_mov_b32 v34, 0\n\t" "v_mov_b32 v35, 0\n\t"
          DR(16,19,0) DR(20,23,16) DR(24,27,32) DR(28,31,48)
          "s_waitcnt lgkmcnt(0)\n\t"
          C0(16,100,101,102,103) C0(17,104,105,106,107)
          C0(18,108,109,110,111) C0(19,112,113,114,115)
          C0(20,116,117,118,119) C0(21,120,121,122,123)
          C0(22,124,125,126,127) C0(23,128,129,130,131)
          C0(24,132,133,134,135) C0(25,136,137,138,139)
          C0(26,140,141,142,143) C0(27,144,145,146,147)
          C0(28,148,149,150,151) C0(29,152,153,154,155)
          C0(30,156,157,158,159) C0(31,160,161,162,163)
          "v_mov_b32 %0, v32\n\t" "v_mov_b32 %1, v33\n\t"
          "v_mov_b32 %2, v34\n\t" "v_mov_b32 %3, v35\n\t"
          : "=v"(a0), "=v"(a1), "=v"(a2), "=v"(a3)
          : "v"(haddr)
          : "v16","v17","v18","v19","v20","v21","v22","v23",
            "v24","v25","v26","v27","v28","v29","v30","v31",
            "v32","v33","v34","v35","memory");
        a0 += __shfl_xor(a0, 1); a1 += __shfl_xor(a1, 1);
        a2 += __shfl_xor(a2, 1); a3 += __shfl_xor(a3, 1);
        a0 += __shfl_xor(a0, 2); a1 += __shfl_xor(a1, 2);
        a2 += __shfl_xor(a2, 2); a3 += __shfl_xor(a3, 2);
        float s1 = (q & 1) ? a1 : a0;
        float s2 = (q & 1) ? a3 : a2;
        float pre = ((q & 2) ? s2 : s1) + fmaf(yq0, wi0, bb);
        float h = gate_update(pre, r, c);
        if (r == 3) smem[nxt * 64 + e] = h;
        yq0 = yq1; yq1 = yq2; yq2 = yq3; yq3 = y_nxt;
      }
      __syncthreads();
    }
  } else {
    // ===== layer 1: weights -> v[100:227], ONCE =====
    unsigned long long wbase =
        (unsigned long long)(uintptr_t)(ws + 16384 + l * 128);
    asm volatile(
      GL(100,103,0)   GL(104,107,16)  GL(108,111,32)  GL(112,115,48)
      GL(116,119,64)  GL(120,123,80)  GL(124,127,96)  GL(128,131,112)
      GL(132,135,128) GL(136,139,144) GL(140,143,160) GL(144,147,176)
      GL(148,151,192) GL(152,155,208) GL(156,159,224) GL(160,163,240)
      GL(164,167,256) GL(168,171,272) GL(172,175,288) GL(176,179,304)
      GL(180,183,320) GL(184,187,336) GL(188,191,352) GL(192,195,368)
      GL(196,199,384) GL(200,203,400) GL(204,207,416) GL(208,211,432)
      GL(212,215,448) GL(216,219,464) GL(220,223,480) GL(224,227,496)
      "s_waitcnt vmcnt(0)\n\t"
      :: "v"(wbase)
      : "v100","v101","v102","v103","v104","v105","v106","v107",
        "v108","v109","v110","v111","v112","v113","v114","v115",
        "v116","v117","v118","v119","v120","v121","v122","v123",
        "v124","v125","v126","v127","v128","v129","v130","v131",
        "v132","v133","v134","v135","v136","v137","v138","v139",
        "v140","v141","v142","v143","v144","v145","v146","v147",
        "v148","v149","v150","v151","v152","v153","v154","v155",
        "v156","v157","v158","v159","v160","v161","v162","v163",
        "v164","v165","v166","v167","v168","v169","v170","v171",
        "v172","v173","v174","v175","v176","v177","v178","v179",
        "v180","v181","v182","v183","v184","v185","v186","v187",
        "v188","v189","v190","v191","v192","v193","v194","v195",
        "v196","v197","v198","v199","v200","v201","v202","v203",
        "v204","v205","v206","v207","v208","v209","v210","v211",
        "v212","v213","v214","v215","v216","v217","v218","v219",
        "v220","v221","v222","v223","v224","v225","v226","v227","memory");

    float bb = bih1[jrow] + bhh1[jrow];
    // h operand chunk: q=0: h0[0:32), q=1: h0[32:64), q=2: h1[0:32), q=3: h1[32:64)
    const float* hbase = ((q < 2) ? smem : smem + 136) + 32 * (q & 1);
    float c = 0.f;

    #pragma unroll 1
    for (int s = 0; s < T + 2; ++s) {
      const int cur = s & 1, nxt = cur ^ 1;
      // ---- layer 1: h1(s-1) from h0[cur]=h0(s-1), h1[cur]=h1(s-2) ----
      if (s >= 1 && s <= T) {
        unsigned haddr = (unsigned)(uintptr_t)(hbase + cur * 64);
        float a0, a1, a2, a3;
        asm volatile(
          "v_mov_b32 v48, 0\n\t" "v_mov_b32 v49, 0\n\t"
          "v_mov_b32 v50, 0\n\t" "v_mov_b32 v51, 0\n\t"
          DR(16,19,0)  DR(20,23,16) DR(24,27,32) DR(28,31,48)
          DR(32,35,64) DR(36,39,80) DR(40,43,96) DR(44,47,112)
          "s_waitcnt lgkmcnt(0)\n\t"
          C1(16,100,101,102,103) C1(17,104,105,106,107)
          C1(18,108,109,110,111) C1(19,112,113,114,115)
          C1(20,116,117,118,119) C1(21,120,121,122,123)
          C1(22,124,125,126,127) C1(23,128,129,130,131)
          C1(24,132,133,134,135) C1(25,136,137,138,139)
          C1(26,140,141,142,143) C1(27,144,145,146,147)
          C1(28,148,149,150,151) C1(29,152,153,154,155)
          C1(30,156,157,158,159) C1(31,160,161,162,163)
          C1(32,164,165,166,167) C1(33,168,169,170,171)
          C1(34,172,173,174,175) C1(35,176,177,178,179)
          C1(36,180,181,182,183) C1(37,184,185,186,187)
          C1(38,188,189,190,191) C1(39,192,193,194,195)
          C1(40,196,197,198,199) C1(41,200,201,202,203)
          C1(42,204,205,206,207) C1(43,208,209,210,211)
          C1(44,212,213,214,215) C1(45,216,217,218,219)
          C1(46,220,221,222,223) C1(47,224,225,226,227)
          "v_mov_b32 %0, v48\n\t" "v_mov_b32 %1, v49\n\t"
          "v_mov_b32 %2, v50\n\t" "v_mov_b32 %3, v51\n\t"
          : "=v"(a0), "=v"(a1), "=v"(a2), "=v"(a3)
          : "v"(haddr)
          : "v16","v17","v18","v19","v20","v21","v22","v23",
            "v24","v25","v26","v27","v28","v29","v30","v31",
            "v32","v33","v34","v35","v36","v37","v38","v39",
            "v40","v41","v42","v43","v44","v45","v46","v47",
            "v48","v49","v50","v51","memory");
        a0 += __shfl_xor(a0, 1); a1 += __shfl_xor(a1, 1);
        a2 += __shfl_xor(a2, 1); a3 += __shfl_xor(a3, 1);
        a0 += __shfl_xor(a0, 2); a1 += __shfl_xor(a1, 2);
        a2 += __shfl_xor(a2, 2); a3 += __shfl_xor(a3, 2);
        float s1 = (q & 1) ? a1 : a0;
        float s2 = (q & 1) ? a3 : a2;
        float pre = ((q & 2) ? s2 : s1) + bb;
        float h = gate_update(pre, r, c);
        if (r == 3) smem[136 + nxt * 64 + e] = h;
      }
      __syncthreads();
    }
  }
}

extern "C" void kernel_launch(void* const* d_in, const int* in_sizes, int n_in,
                              void* d_out, int out_size, void* d_ws, size_t ws_size,
                              hipStream_t stream) {
  const float* y    = (const float*)d_in[0];
  const float* Wih0 = (const float*)d_in[1];
  const float* Whh0 = (const float*)d_in[2];
  const float* bih0 = (const float*)d_in[3];
  const float* bhh0 = (const float*)d_in[4];
  const float* Wih1 = (const float*)d_in[5];
  const float* Whh1 = (const float*)d_in[6];
  const float* bih1 = (const float*)d_in[7];
  const float* bhh1 = (const float*)d_in[8];
  const float* Wlin = (const float*)d_in[9];
  const float* blin = (const float*)d_in[10];
  float* ws = (float*)d_ws;                      // 49152 floats = 192KB

  pack_slices<<<dim3(192), dim3(256), 0, stream>>>(Whh0, Wih1, Whh1, ws);
  rnn_fused<<<dim3(1), dim3(512), 0, stream>>>(
      y, Wih0, bih0, bhh0, bih1, bhh1, Wlin, blin, ws, (float*)d_out);
}